// Round 9
// baseline (228.901 us; speedup 1.0000x reference)
//
#include <hip/hip_runtime.h>
#include <hip/hip_bf16.h>

#define Bq 2
#define Tt 2048
#define Cc 2048
#define Hh 16
#define Dd 128
#define Gg 4

using bf16 = __hip_bfloat16;
typedef __attribute__((ext_vector_type(8))) short short8;
typedef __attribute__((ext_vector_type(4))) float f32x4;
typedef __attribute__((ext_vector_type(16))) float f32x16;
typedef unsigned int u32;

__device__ __forceinline__ void gload_lds16(const void* g, void* l) {
    __builtin_amdgcn_global_load_lds(
        (const __attribute__((address_space(1))) unsigned int*)g,
        (__attribute__((address_space(3))) unsigned int*)l, 16, 0, 0);
}

__device__ __forceinline__ u32 cvtpk(float lo, float hi) {
    u32 d;
    asm("v_cvt_pk_bf16_f32 %0, %1, %2" : "=v"(d) : "v"(lo), "v"(hi));
    return d;
}

// ---------------- cast x (f32 -> bf16), 4 elems/thread ----------------
__global__ void k_cast_bf16(const float* __restrict__ in, bf16* __restrict__ out, int n4) {
    int i = blockIdx.x * blockDim.x + threadIdx.x;
    if (i >= n4) return;
    float4 v = ((const float4*)in)[i];
    union { bf16 h[4]; uint2 u; } u;
    u.h[0] = __float2bfloat16(v.x);
    u.h[1] = __float2bfloat16(v.y);
    u.h[2] = __float2bfloat16(v.z);
    u.h[3] = __float2bfloat16(v.w);
    ((uint2*)out)[i] = u.u;
}

// ---------------- cast + transpose: in[rows][cols] f32 -> out[cols][ostride] bf16 ----------------
__global__ void k_cast_transpose(const float* __restrict__ in, bf16* __restrict__ out,
                                 int rows, int cols, int ostride) {
    __shared__ float tile[32][33];
    int c0 = blockIdx.x * 32, r0 = blockIdx.y * 32;
    int tx = threadIdx.x, ty = threadIdx.y;  // block (32,8)
    #pragma unroll
    for (int k = 0; k < 4; ++k)
        tile[ty + 8*k][tx] = in[(size_t)(r0 + ty + 8*k) * cols + c0 + tx];
    __syncthreads();
    #pragma unroll
    for (int k = 0; k < 4; ++k)
        out[(size_t)(c0 + ty + 8*k) * ostride + r0 + tx] = __float2bfloat16(tile[tx][ty + 8*k]);
}

// ---------------- bf16 transpose of V columns of QKV -> Vt[b][g][d][t] ----------------
__global__ void k_vt(const bf16* __restrict__ QKV, bf16* __restrict__ Vt) {
    __shared__ bf16 tile[64][65];
    const int d0 = blockIdx.x * 64, t0 = blockIdx.y * 64;
    const int bg = blockIdx.z;
    const int b = bg >> 2, g = bg & 3;
    const int tx = threadIdx.x, ty = threadIdx.y;
    const bf16* src = QKV + (size_t)(b * Tt) * 3072 + 2560 + g * 128;
    #pragma unroll
    for (int k = 0; k < 8; ++k)
        tile[ty + 8*k][tx] = src[(size_t)(t0 + ty + 8*k) * 3072 + d0 + tx];
    __syncthreads();
    bf16* dst = Vt + (size_t)bg * Dd * Tt;
    #pragma unroll
    for (int k = 0; k < 8; ++k)
        dst[(size_t)(d0 + ty + 8*k) * Tt + t0 + tx] = tile[tx][ty + 8*k];
}

// ---------------- GEMM: C[M][N] = A[M][K] @ Bt[N][K]^T, bf16 in, f32 acc ----------------
// Proven structure: 128x128 tile, BK=64, 4 waves, ~904 TF.
template<int OUTF32>
__global__ __launch_bounds__(256)
void k_gemm_bt(const bf16* __restrict__ A, const bf16* __restrict__ Bt,
               void* __restrict__ C, int M, int N, int K) {
    __shared__ __align__(16) bf16 As[128 * 64];
    __shared__ __align__(16) bf16 Bs[128 * 64];
    const int lane = threadIdx.x & 63;
    const int wave = threadIdx.x >> 6;
    const int row0 = blockIdx.y * 128;
    const int col0 = blockIdx.x * 128;
    const int wm = wave >> 1, wn = wave & 1;
    f32x4 acc[4][4] = {};

    const int srow = lane >> 3;
    const int schunk = ((lane & 7) ^ srow) * 8;

    for (int k0 = 0; k0 < K; k0 += 64) {
        #pragma unroll
        for (int j = 0; j < 4; ++j) {
            const int c = j * 4 + wave;
            const int rt = c * 8 + srow;
            gload_lds16(A  + (size_t)(row0 + rt) * K + k0 + schunk, As + c * 512);
            gload_lds16(Bt + (size_t)(col0 + rt) * K + k0 + schunk, Bs + c * 512);
        }
        __syncthreads();
        #pragma unroll
        for (int kk = 0; kk < 2; ++kk) {
            short8 af[4], bfr[4];
            #pragma unroll
            for (int i = 0; i < 4; ++i) {
                const int ra = wm * 64 + i * 16 + (lane & 15);
                af[i] = *(const short8*)((const char*)As + ra * 128 +
                        ((kk * 64 + (lane >> 4) * 16) ^ ((ra & 7) << 4)));
                const int rb = wn * 64 + i * 16 + (lane & 15);
                bfr[i] = *(const short8*)((const char*)Bs + rb * 128 +
                        ((kk * 64 + (lane >> 4) * 16) ^ ((rb & 7) << 4)));
            }
            __builtin_amdgcn_s_setprio(1);
            #pragma unroll
            for (int i = 0; i < 4; ++i)
                #pragma unroll
                for (int j = 0; j < 4; ++j)
                    acc[i][j] = __builtin_amdgcn_mfma_f32_16x16x32_bf16(af[i], bfr[j], acc[i][j], 0, 0, 0);
            __builtin_amdgcn_s_setprio(0);
        }
        __syncthreads();
    }

    const int crow0 = row0 + wm * 64 + (lane >> 4) * 4;
    const int ccol0 = col0 + wn * 64 + (lane & 15);
    #pragma unroll
    for (int i = 0; i < 4; ++i)
        #pragma unroll
        for (int j = 0; j < 4; ++j)
            #pragma unroll
            for (int r = 0; r < 4; ++r) {
                const size_t idx = (size_t)(crow0 + i * 16 + r) * N + ccol0 + j * 16;
                const float v = acc[i][j][r];
                if (OUTF32) ((float*)C)[idx] = v;
                else        ((bf16*)C)[idx] = __float2bfloat16(v);
            }
}

// ---------------- RMSNorm + RoPE + scatter Q,K; Q pre-scaled by D^-1/2 ----------------
__global__ void k_qkv_post(const bf16* __restrict__ QKV,
                           const float* __restrict__ cosT, const float* __restrict__ sinT,
                           const float* __restrict__ qs, const float* __restrict__ ks,
                           bf16* __restrict__ Qr, bf16* __restrict__ Kr) {
    const int bt = blockIdx.x;
    const int b = bt >> 11;
    const int t = bt & 2047;
    const int lane = threadIdx.x & 63;
    const int wave = threadIdx.x >> 6;
    const float c1 = cosT[t * 128 + lane],      c2 = cosT[t * 128 + 64 + lane];
    const float s1 = sinT[t * 128 + lane],      s2 = sinT[t * 128 + 64 + lane];
    const float qs1 = qs[lane], qs2 = qs[lane + 64];
    const float ks1 = ks[lane], ks2 = ks[lane + 64];
    const bf16* rowb = QKV + (size_t)bt * 3072;
    for (int rr = wave; rr < 20; rr += 4) {
        const bf16* src = rowb + rr * 128;
        const float x1 = __bfloat162float(src[lane]);
        const float x2 = __bfloat162float(src[lane + 64]);
        bf16* dst;
        if (rr < 16) dst = Qr + ((size_t)(b * Hh + rr) * Tt + t) * 128;
        else         dst = Kr + ((size_t)(b * Gg + (rr - 16)) * Tt + t) * 128;
        float ssum = x1 * x1 + x2 * x2;
        #pragma unroll
        for (int o = 32; o > 0; o >>= 1) ssum += __shfl_xor(ssum, o);
        const float inv = rsqrtf(ssum * (1.0f / 128.0f) + 1e-6f);
        const float post = (rr < 16) ? 0.08838834764831845f : 1.0f;  // fold 1/sqrt(D) into Q
        const float sc1 = ((rr < 16) ? qs1 : ks1) * inv;
        const float sc2 = ((rr < 16) ? qs2 : ks2) * inv;
        const float y1 = x1 * sc1;
        const float y2 = x2 * sc2;
        dst[lane]      = __float2bfloat16((y1 * c1 - y2 * s1) * post);
        dst[lane + 64] = __float2bfloat16((y2 * c2 + y1 * s2) * post);
    }
}

// ---------------- causal flash attention, GQA, swapped-QK^T in-register softmax ----------------
// 4 waves = (q-sub 0/1) x (kt-half 0/1). QK^T = mfma32x32(K,Q) -> lane owns P column q=lane&31,
// kt in regs. cvt_pk + shfl_xor(32) exchange packs P straight into PV A-frags (no P LDS
// round-trip). m=0 softmax (|S| <= sqrt(128), Cauchy-Schwarz on RMSNorm'd Q,K). Per-pass O/l
// merge across kt-half wave pairs via LDS. Fold-paired (p,31-p): 512 blocks, 33 balanced iters.
__global__ __launch_bounds__(256)
void k_attn(const bf16* __restrict__ Qr, const bf16* __restrict__ Kr,
            const bf16* __restrict__ Vt, bf16* __restrict__ AO) {
    __shared__ __align__(16) bf16 Ksm[2][64 * 128];
    __shared__ __align__(16) bf16 Vsm[2][128 * 64];
    const int id = blockIdx.x;
    const int bg = id & 7;            // one (b,g) per XCD -> K/V L2-resident
    const int wid = id >> 3;          // 0..63
    const int pair = wid & 15;
    const int hg = wid >> 4;          // 0..3
    const int b = bg >> 2, g = bg & 3;
    const int h = g * 4 + hg;
    const int lane = threadIdx.x & 63;
    const int w = threadIdx.x >> 6;
    const int qsub = w >> 1, khalf = w & 1;
    const int l31 = lane & 31, hi32 = lane >> 5;

    const bf16* Kbase = Kr + (size_t)(b * Gg + g) * Tt * Dd;
    const bf16* Vbase = Vt + (size_t)(b * Gg + g) * Dd * Tt;

    for (int pass = 0; pass < 2; ++pass) {
        const int qt = pass ? (31 - pair) : pair;
        const int nkv = qt + 1;
        const int qbase = qt * 64 + qsub * 32;

        // Q fragments (B operand): lane q = qbase + l31, d = dstep*16 + hi32*8 + j
        short8 qf[8];
        {
            const bf16* Qp = Qr + ((size_t)(b * Hh + h) * Tt + qbase + l31) * 128;
            #pragma unroll
            for (int d = 0; d < 8; ++d)
                qf[d] = *(const short8*)(Qp + d * 16 + hi32 * 8);
        }

        f32x16 oacc[4] = {};
        float l_run = 0.f;

        // stage tile 0 into buffer 0
        {
            #pragma unroll
            for (int j = 0; j < 4; ++j) {
                const int c = j * 4 + w;
                const int rtk = c * 4 + (lane >> 4);
                const int chk = (lane & 15) ^ (rtk & 7);
                gload_lds16(Kbase + (size_t)rtk * 128 + chk * 8, Ksm[0] + c * 512);
                const int rtv = c * 8 + (lane >> 3);
                const int chv = (lane & 7) ^ ((lane >> 3) & 7);
                gload_lds16(Vbase + (size_t)rtv * Tt + chv * 8, Vsm[0] + c * 512);
            }
        }

        int cur = 0;
        for (int tk = 0; tk < nkv; ++tk) {
            __syncthreads();   // buf[cur] staged (barrier drains vmcnt)

            if (tk + 1 < nkv) {   // prefetch next tile into other buffer
                const int k0n = (tk + 1) * 64;
                #pragma unroll
                for (int j = 0; j < 4; ++j) {
                    const int c = j * 4 + w;
                    const int rtk = c * 4 + (lane >> 4);
                    const int chk = (lane & 15) ^ (rtk & 7);
                    gload_lds16(Kbase + (size_t)(k0n + rtk) * 128 + chk * 8, Ksm[cur ^ 1] + c * 512);
                    const int rtv = c * 8 + (lane >> 3);
                    const int chv = (lane & 7) ^ ((lane >> 3) & 7);
                    gload_lds16(Vbase + (size_t)rtv * Tt + k0n + chv * 8, Vsm[cur ^ 1] + c * 512);
                }
            }

            const bf16* Ks = Ksm[cur];
            const bf16* Vs = Vsm[cur];

            // swapped QK^T: S^T[kt][q] over this wave's kt-half; split dep chain in two
            f32x16 sa = {}, sb = {};
            const int krow = khalf * 32 + l31;
            const int kbyte = krow * 256;
            const int kswz = (krow & 7) << 4;
            __builtin_amdgcn_s_setprio(1);
            #pragma unroll
            for (int d = 0; d < 4; ++d) {
                short8 kf = *(const short8*)((const char*)Ks + kbyte + ((d * 32 + hi32 * 16) ^ kswz));
                sa = __builtin_amdgcn_mfma_f32_32x32x16_bf16(kf, qf[d], sa, 0, 0, 0);
            }
            #pragma unroll
            for (int d = 4; d < 8; ++d) {
                short8 kf = *(const short8*)((const char*)Ks + kbyte + ((d * 32 + hi32 * 16) ^ kswz));
                sb = __builtin_amdgcn_mfma_f32_32x32x16_bf16(kf, qf[d], sb, 0, 0, 0);
            }
            __builtin_amdgcn_s_setprio(0);

            float p[16];
            const int qrow_l = qbase + l31;
            const int k0 = tk * 64 + khalf * 32;
            #pragma unroll
            for (int r = 0; r < 16; ++r) {
                float v = sa[r] + sb[r];
                if (tk == nkv - 1) {   // diagonal tile mask
                    const int ktg = k0 + (r & 3) + 8 * (r >> 2) + 4 * hi32;
                    if (ktg > qrow_l) v = -1e30f;
                }
                p[r] = __expf(v);
                l_run += p[r];
            }

            // pack P -> PV A-frags via exact lane l <-> l^32 exchange (+ per-half select):
            // hi0 lane needs kt {0..7} = {a0,a1} + partner's {a0,a1}; hi1 needs kt {8..15}.
            short8 pa[2];
            #pragma unroll
            for (int s = 0; s < 2; ++s) {
                const int bidx = s * 8;
                u32 a0 = cvtpk(p[bidx + 0], p[bidx + 1]);
                u32 a1 = cvtpk(p[bidx + 2], p[bidx + 3]);
                u32 b0 = cvtpk(p[bidx + 4], p[bidx + 5]);
                u32 b1 = cvtpk(p[bidx + 6], p[bidx + 7]);
                u32 xa0 = (u32)__shfl_xor((int)a0, 32);
                u32 xa1 = (u32)__shfl_xor((int)a1, 32);
                u32 xb0 = (u32)__shfl_xor((int)b0, 32);
                u32 xb1 = (u32)__shfl_xor((int)b1, 32);
                union { u32 wq[4]; short8 s8; } uu;
                uu.wq[0] = hi32 ? xb0 : a0;
                uu.wq[1] = hi32 ? xb1 : a1;
                uu.wq[2] = hi32 ? b0 : xa0;
                uu.wq[3] = hi32 ? b1 : xa1;
                pa[s] = uu.s8;
            }

            // PV: oacc[db] += P(32q x 32kt-half) @ V(kt x 32d-block)
            __builtin_amdgcn_s_setprio(1);
            #pragma unroll
            for (int db = 0; db < 4; ++db) {
                const int vrow = db * 32 + l31;
                const int vbyte = vrow * 128;
                const int vswz = (vrow & 7) << 4;
                #pragma unroll
                for (int s = 0; s < 2; ++s) {
                    short8 vf = *(const short8*)((const char*)Vs + vbyte +
                                ((khalf * 64 + s * 32 + hi32 * 16) ^ vswz));
                    oacc[db] = __builtin_amdgcn_mfma_f32_32x32x16_bf16(pa[s], vf, oacc[db], 0, 0, 0);
                }
            }
            __builtin_amdgcn_s_setprio(0);
            cur ^= 1;
        }

        // ---- merge kt-half wave pairs (waves 2k and 2k+1) via LDS ----
        __syncthreads();
        float* scO = (float*)(&Ksm[0][0]);     // [qsub][64][64] f32 = 32 KB
        float* scL = (float*)(&Vsm[0][0]);     // [qsub][64] f32
        if (khalf) {
            #pragma unroll
            for (int db = 0; db < 4; ++db)
                #pragma unroll
                for (int r = 0; r < 16; ++r)
                    scO[qsub * 4096 + (db * 16 + r) * 64 + lane] = oacc[db][r];
            scL[qsub * 64 + lane] = l_run;
        }
        __syncthreads();
        if (!khalf) {
            #pragma unroll
            for (int db = 0; db < 4; ++db)
                #pragma unroll
                for (int r = 0; r < 16; ++r)
                    oacc[db][r] += scO[qsub * 4096 + (db * 16 + r) * 64 + lane];
            l_run += scL[qsub * 64 + lane];
            l_run += __shfl_xor(l_run, 32);    // combine hi32 halves -> full row sum

            #pragma unroll
            for (int r = 0; r < 16; ++r) {
                const int qr = (r & 3) + 8 * (r >> 2) + 4 * hi32;
                const float linv = 1.0f / __shfl(l_run, qr);
                const int qrow = qbase + qr;
                bf16* dst = AO + ((size_t)(b * Tt) + qrow) * 2048 + h * 128 + l31;
                #pragma unroll
                for (int db = 0; db < 4; ++db)
                    dst[db * 32] = __float2bfloat16(oacc[db][r] * linv);
            }
        }
        __syncthreads();   // protect LDS before next pass restages
    }
}

extern "C" void kernel_launch(void* const* d_in, const int* in_sizes, int n_in,
                              void* d_out, int out_size, void* d_ws, size_t ws_size,
                              hipStream_t stream) {
    const float* x    = (const float*)d_in[0];
    const float* cosT = (const float*)d_in[2];
    const float* sinT = (const float*)d_in[3];
    const float* Wq   = (const float*)d_in[4];
    const float* Wk   = (const float*)d_in[5];
    const float* Wv   = (const float*)d_in[6];
    const float* Wo   = (const float*)d_in[7];
    const float* qs   = (const float*)d_in[8];
    const float* ks   = (const float*)d_in[9];

    char* ws = (char*)d_ws;
    bf16* xb   = (bf16*)(ws);                    // 16.78 MB
    bf16* Wcat = (bf16*)(ws + 16777216);         // [3072][2048] 12.58 MB
    bf16* Wot  = (bf16*)(ws + 29360128);         // [2048][2048] 8.39 MB
    bf16* QKV  = (bf16*)(ws + 37748736);         // [4096][3072] 25.17 MB
    bf16* Qr   = (bf16*)(ws + 62914560);         // [B][H][T][D] 16.78 MB
    bf16* Kr   = (bf16*)(ws + 79691776);         // [B][G][T][D] 4.19 MB
    bf16* Vtp  = (bf16*)(ws + 83886080);         // [B][G][D][T] 4.19 MB
    bf16* AO   = (bf16*)(ws + 88080384);         // [B*T][H*D]  16.78 MB

    k_cast_bf16<<<8192, 256, 0, stream>>>(x, xb, 2097152);
    dim3 tb(32, 8);
    k_cast_transpose<<<dim3(64, 64), tb, 0, stream>>>(Wq, Wcat, 2048, 2048, 2048);
    k_cast_transpose<<<dim3(16, 64), tb, 0, stream>>>(Wk, Wcat + (size_t)2048 * 2048, 2048, 512, 2048);
    k_cast_transpose<<<dim3(16, 64), tb, 0, stream>>>(Wv, Wcat + (size_t)2560 * 2048, 2048, 512, 2048);
    k_cast_transpose<<<dim3(64, 64), tb, 0, stream>>>(Wo, Wot, 2048, 2048, 2048);

    k_gemm_bt<0><<<dim3(24, 32), 256, 0, stream>>>(xb, Wcat, QKV, 4096, 3072, 2048);
    k_qkv_post<<<4096, 256, 0, stream>>>(QKV, cosT, sinT, qs, ks, Qr, Kr);
    k_vt<<<dim3(2, 32, 8), dim3(64, 8), 0, stream>>>(QKV, Vtp);
    k_attn<<<512, 256, 0, stream>>>(Qr, Kr, Vtp, AO);
    k_gemm_bt<1><<<dim3(16, 32), 256, 0, stream>>>(AO, Wot, d_out, 4096, 2048, 2048);
}

// Round 10
// 199.698 us; speedup vs baseline: 1.1462x; 1.1462x over previous
//
#include <hip/hip_runtime.h>
#include <hip/hip_bf16.h>

#define Bq 2
#define Tt 2048
#define Cc 2048
#define Hh 16
#define Dd 128
#define Gg 4

using bf16 = __hip_bfloat16;
typedef __attribute__((ext_vector_type(8))) short short8;
typedef __attribute__((ext_vector_type(4))) float f32x4;

__device__ __forceinline__ void gload_lds16(const void* g, void* l) {
    __builtin_amdgcn_global_load_lds(
        (const __attribute__((address_space(1))) unsigned int*)g,
        (__attribute__((address_space(3))) unsigned int*)l, 16, 0, 0);
}

#define MEMBAR() asm volatile("" ::: "memory")

// ---------------- cast x (f32 -> bf16), 4 elems/thread ----------------
__global__ void k_cast_bf16(const float* __restrict__ in, bf16* __restrict__ out, int n4) {
    int i = blockIdx.x * blockDim.x + threadIdx.x;
    if (i >= n4) return;
    float4 v = ((const float4*)in)[i];
    union { bf16 h[4]; uint2 u; } u;
    u.h[0] = __float2bfloat16(v.x);
    u.h[1] = __float2bfloat16(v.y);
    u.h[2] = __float2bfloat16(v.z);
    u.h[3] = __float2bfloat16(v.w);
    ((uint2*)out)[i] = u.u;
}

// ---------------- cast + transpose: in[rows][cols] f32 -> out[cols][ostride] bf16 ----------------
__global__ void k_cast_transpose(const float* __restrict__ in, bf16* __restrict__ out,
                                 int rows, int cols, int ostride) {
    __shared__ float tile[32][33];
    int c0 = blockIdx.x * 32, r0 = blockIdx.y * 32;
    int tx = threadIdx.x, ty = threadIdx.y;  // block (32,8)
    #pragma unroll
    for (int k = 0; k < 4; ++k)
        tile[ty + 8*k][tx] = in[(size_t)(r0 + ty + 8*k) * cols + c0 + tx];
    __syncthreads();
    #pragma unroll
    for (int k = 0; k < 4; ++k)
        out[(size_t)(c0 + ty + 8*k) * ostride + r0 + tx] = __float2bfloat16(tile[tx][ty + 8*k]);
}

// ---------------- bf16 transpose of V columns of QKV -> Vt[b][g][d][t] ----------------
__global__ void k_vt(const bf16* __restrict__ QKV, bf16* __restrict__ Vt) {
    __shared__ bf16 tile[64][65];
    const int d0 = blockIdx.x * 64, t0 = blockIdx.y * 64;
    const int bg = blockIdx.z;
    const int b = bg >> 2, g = bg & 3;
    const int tx = threadIdx.x, ty = threadIdx.y;
    const bf16* src = QKV + (size_t)(b * Tt) * 3072 + 2560 + g * 128;
    #pragma unroll
    for (int k = 0; k < 8; ++k)
        tile[ty + 8*k][tx] = src[(size_t)(t0 + ty + 8*k) * 3072 + d0 + tx];
    __syncthreads();
    bf16* dst = Vt + (size_t)bg * Dd * Tt;
    #pragma unroll
    for (int k = 0; k < 8; ++k)
        dst[(size_t)(d0 + ty + 8*k) * Tt + t0 + tx] = tile[tx][ty + 8*k];
}

// ---------------- 256x256 8-wave 4-phase GEMM: C = A @ Bt^T ----------------
// BK=64. LDS: 2 buf x 4 half-tiles [128][64] (A0,B0,B1,A1) = 128 KB. Per phase:
// stage 1 half-tile of t+1, vmcnt(6) (3 half-tiles stay in flight -> ~4-phase latency
// cover), raw barrier, ds_read frags, 16 MFMA. Phase->quadrant order (m0n0),(m0n1),
// (m1n1),(m1n0) makes needed half-tiles a prefix of staging order. End barrier per
// K-tile closes the buf WAR hazard. Wave grid 2x4; per-wave C = 128x64.
template<int OUTF32>
__global__ __launch_bounds__(512, 2)
void k_gemm256(const bf16* __restrict__ A, const bf16* __restrict__ Bt,
               void* __restrict__ C, int M, int N, int K, int nbx) {
    __shared__ __align__(16) bf16 Ls[2][4][128 * 64];
    const int tid = threadIdx.x;
    const int lane = tid & 63;
    const int wid = tid >> 6;
    const int wm = wid >> 2, wn = wid & 3;

    const int nb = gridDim.x;
    const int cpx = nb >> 3;                    // nb % 8 == 0 (192)
    const int id = blockIdx.x;
    const int sid = (id & 7) * cpx + (id >> 3);
    const int bx = sid % nbx, by = sid / nbx;
    const int row0 = by * 256, col0 = bx * 256;

    const int NT = K >> 6;
    f32x4 acc[2][4][2][2] = {};

    // ht: 0=A half0, 1=B half0, 2=B half1, 3=A half1
#define STAGE_HT(bufq, tt, ht) {                                               \
        const bool isB_ = ((ht) == 1 || (ht) == 2);                            \
        const int half_ = ((ht) >= 2) ? 128 : 0;                               \
        _Pragma("unroll")                                                      \
        for (int c_ = 0; c_ < 2; ++c_) {                                       \
            const int r_ = c_ * 64 + (tid >> 3);                               \
            const int ch_ = (tid & 7) ^ (r_ & 7);                              \
            const bf16* gs_ = (isB_ ? Bt + (size_t)(col0 + half_ + r_) * K     \
                                    : A  + (size_t)(row0 + half_ + r_) * K)    \
                              + (tt) * 64 + ch_ * 8;                           \
            gload_lds16(gs_, &Ls[bufq][ht][c_ * 4096] + tid * 8);              \
        } }

    // prologue: tile 0, all 4 half-tiles -> buf 0
    STAGE_HT(0, 0, 0); STAGE_HT(0, 0, 1); STAGE_HT(0, 0, 2); STAGE_HT(0, 0, 3);

    for (int t = 0; t < NT; ++t) {
        const int p = t & 1, q = p ^ 1;
        const bool pf = (t + 1 < NT);
        const bf16* hA0 = Ls[p][0];
        const bf16* hB0 = Ls[p][1];
        const bf16* hB1 = Ls[p][2];
        const bf16* hA1 = Ls[p][3];

        short8 af[4][2], bb0[2][2], bb1[2][2];

        auto rdA = [&](const bf16* hh, int i, int kk) -> short8 {
            const int ra = wm * 64 + i * 16 + (lane & 15);
            return *(const short8*)((const char*)hh + ra * 128 +
                   ((kk * 64 + (lane >> 4) * 16) ^ ((ra & 7) << 4)));
        };
        auto rdB = [&](const bf16* hh, int j, int kk) -> short8 {
            const int rb = wn * 32 + j * 16 + (lane & 15);
            return *(const short8*)((const char*)hh + rb * 128 +
                   ((kk * 64 + (lane >> 4) * 16) ^ ((rb & 7) << 4)));
        };

        // ---- phase 0: quadrant (m0, n0); needs ht0, ht1 ----
        if (pf) { STAGE_HT(q, t + 1, 0); asm volatile("s_waitcnt vmcnt(6)" ::: "memory"); }
        else    { asm volatile("s_waitcnt vmcnt(4)" ::: "memory"); }
        __builtin_amdgcn_s_barrier(); MEMBAR();
        #pragma unroll
        for (int i = 0; i < 4; ++i)
            #pragma unroll
            for (int kk = 0; kk < 2; ++kk) af[i][kk] = rdA(hA0, i, kk);
        #pragma unroll
        for (int j = 0; j < 2; ++j)
            #pragma unroll
            for (int kk = 0; kk < 2; ++kk) bb0[j][kk] = rdB(hB0, j, kk);
        __builtin_amdgcn_s_setprio(1);
        #pragma unroll
        for (int i = 0; i < 4; ++i)
            #pragma unroll
            for (int j = 0; j < 2; ++j)
                #pragma unroll
                for (int kk = 0; kk < 2; ++kk)
                    acc[0][i][0][j] = __builtin_amdgcn_mfma_f32_16x16x32_bf16(af[i][kk], bb0[j][kk], acc[0][i][0][j], 0, 0, 0);
        __builtin_amdgcn_s_setprio(0);

        // ---- phase 1: quadrant (m0, n1); needs ht2 ----
        MEMBAR();
        if (pf) { STAGE_HT(q, t + 1, 1); asm volatile("s_waitcnt vmcnt(6)" ::: "memory"); }
        else    { asm volatile("s_waitcnt vmcnt(2)" ::: "memory"); }
        __builtin_amdgcn_s_barrier(); MEMBAR();
        #pragma unroll
        for (int j = 0; j < 2; ++j)
            #pragma unroll
            for (int kk = 0; kk < 2; ++kk) bb1[j][kk] = rdB(hB1, j, kk);
        __builtin_amdgcn_s_setprio(1);
        #pragma unroll
        for (int i = 0; i < 4; ++i)
            #pragma unroll
            for (int j = 0; j < 2; ++j)
                #pragma unroll
                for (int kk = 0; kk < 2; ++kk)
                    acc[0][i][1][j] = __builtin_amdgcn_mfma_f32_16x16x32_bf16(af[i][kk], bb1[j][kk], acc[0][i][1][j], 0, 0, 0);
        __builtin_amdgcn_s_setprio(0);

        // ---- phase 2: quadrant (m1, n1); needs ht3 ----
        MEMBAR();
        if (pf) { STAGE_HT(q, t + 1, 2); asm volatile("s_waitcnt vmcnt(6)" ::: "memory"); }
        else    { asm volatile("s_waitcnt vmcnt(0)" ::: "memory"); }
        __builtin_amdgcn_s_barrier(); MEMBAR();
        #pragma unroll
        for (int i = 0; i < 4; ++i)
            #pragma unroll
            for (int kk = 0; kk < 2; ++kk) af[i][kk] = rdA(hA1, i, kk);
        __builtin_amdgcn_s_setprio(1);
        #pragma unroll
        for (int i = 0; i < 4; ++i)
            #pragma unroll
            for (int j = 0; j < 2; ++j)
                #pragma unroll
                for (int kk = 0; kk < 2; ++kk)
                    acc[1][i][1][j] = __builtin_amdgcn_mfma_f32_16x16x32_bf16(af[i][kk], bb1[j][kk], acc[1][i][1][j], 0, 0, 0);
        __builtin_amdgcn_s_setprio(0);

        // ---- phase 3: quadrant (m1, n0); no new half-tile needed, no reads ----
        MEMBAR();
        if (pf) STAGE_HT(q, t + 1, 3);
        __builtin_amdgcn_s_setprio(1);
        #pragma unroll
        for (int i = 0; i < 4; ++i)
            #pragma unroll
            for (int j = 0; j < 2; ++j)
                #pragma unroll
                for (int kk = 0; kk < 2; ++kk)
                    acc[1][i][0][j] = __builtin_amdgcn_mfma_f32_16x16x32_bf16(af[i][kk], bb0[j][kk], acc[1][i][0][j], 0, 0, 0);
        __builtin_amdgcn_s_setprio(0);
        MEMBAR();
        __builtin_amdgcn_s_barrier();   // end of K-tile: all reads of buf[p] retired
        MEMBAR();
    }
#undef STAGE_HT

    #pragma unroll
    for (int mh = 0; mh < 2; ++mh)
        #pragma unroll
        for (int i = 0; i < 4; ++i)
            #pragma unroll
            for (int nh = 0; nh < 2; ++nh)
                #pragma unroll
                for (int j = 0; j < 2; ++j)
                    #pragma unroll
                    for (int r = 0; r < 4; ++r) {
                        const int crow = row0 + mh * 128 + wm * 64 + i * 16 + (lane >> 4) * 4 + r;
                        const int ccol = col0 + nh * 128 + wn * 32 + j * 16 + (lane & 15);
                        const size_t idx = (size_t)crow * N + ccol;
                        const float v = acc[mh][i][nh][j][r];
                        if (OUTF32) ((float*)C)[idx] = v;
                        else        ((bf16*)C)[idx] = __float2bfloat16(v);
                    }
}

// ---------------- GEMM: C[M][N] = A[M][K] @ Bt[N][K]^T (proven 128^2, ~904 TF) ----------------
template<int OUTF32>
__global__ __launch_bounds__(256)
void k_gemm_bt(const bf16* __restrict__ A, const bf16* __restrict__ Bt,
               void* __restrict__ C, int M, int N, int K) {
    __shared__ __align__(16) bf16 As[128 * 64];
    __shared__ __align__(16) bf16 Bs[128 * 64];
    const int lane = threadIdx.x & 63;
    const int wave = threadIdx.x >> 6;
    const int row0 = blockIdx.y * 128;
    const int col0 = blockIdx.x * 128;
    const int wm = wave >> 1, wn = wave & 1;
    f32x4 acc[4][4] = {};

    const int srow = lane >> 3;
    const int schunk = ((lane & 7) ^ srow) * 8;

    for (int k0 = 0; k0 < K; k0 += 64) {
        #pragma unroll
        for (int j = 0; j < 4; ++j) {
            const int c = j * 4 + wave;
            const int rt = c * 8 + srow;
            gload_lds16(A  + (size_t)(row0 + rt) * K + k0 + schunk, As + c * 512);
            gload_lds16(Bt + (size_t)(col0 + rt) * K + k0 + schunk, Bs + c * 512);
        }
        __syncthreads();
        #pragma unroll
        for (int kk = 0; kk < 2; ++kk) {
            short8 af[4], bfr[4];
            #pragma unroll
            for (int i = 0; i < 4; ++i) {
                const int ra = wm * 64 + i * 16 + (lane & 15);
                af[i] = *(const short8*)((const char*)As + ra * 128 +
                        ((kk * 64 + (lane >> 4) * 16) ^ ((ra & 7) << 4)));
                const int rb = wn * 64 + i * 16 + (lane & 15);
                bfr[i] = *(const short8*)((const char*)Bs + rb * 128 +
                        ((kk * 64 + (lane >> 4) * 16) ^ ((rb & 7) << 4)));
            }
            __builtin_amdgcn_s_setprio(1);
            #pragma unroll
            for (int i = 0; i < 4; ++i)
                #pragma unroll
                for (int j = 0; j < 4; ++j)
                    acc[i][j] = __builtin_amdgcn_mfma_f32_16x16x32_bf16(af[i], bfr[j], acc[i][j], 0, 0, 0);
            __builtin_amdgcn_s_setprio(0);
        }
        __syncthreads();
    }

    const int crow0 = row0 + wm * 64 + (lane >> 4) * 4;
    const int ccol0 = col0 + wn * 64 + (lane & 15);
    #pragma unroll
    for (int i = 0; i < 4; ++i)
        #pragma unroll
        for (int j = 0; j < 4; ++j)
            #pragma unroll
            for (int r = 0; r < 4; ++r) {
                const size_t idx = (size_t)(crow0 + i * 16 + r) * N + ccol0 + j * 16;
                const float v = acc[i][j][r];
                if (OUTF32) ((float*)C)[idx] = v;
                else        ((bf16*)C)[idx] = __float2bfloat16(v);
            }
}

// ---------------- RMSNorm + RoPE + scatter Q,K; Q pre-scaled by D^-1/2 ----------------
__global__ void k_qkv_post(const bf16* __restrict__ QKV,
                           const float* __restrict__ cosT, const float* __restrict__ sinT,
                           const float* __restrict__ qs, const float* __restrict__ ks,
                           bf16* __restrict__ Qr, bf16* __restrict__ Kr) {
    const int bt = blockIdx.x;
    const int b = bt >> 11;
    const int t = bt & 2047;
    const int lane = threadIdx.x & 63;
    const int wave = threadIdx.x >> 6;
    const float c1 = cosT[t * 128 + lane],      c2 = cosT[t * 128 + 64 + lane];
    const float s1 = sinT[t * 128 + lane],      s2 = sinT[t * 128 + 64 + lane];
    const float qs1 = qs[lane], qs2 = qs[lane + 64];
    const float ks1 = ks[lane], ks2 = ks[lane + 64];
    const bf16* rowb = QKV + (size_t)bt * 3072;
    for (int rr = wave; rr < 20; rr += 4) {
        const bf16* src = rowb + rr * 128;
        const float x1 = __bfloat162float(src[lane]);
        const float x2 = __bfloat162float(src[lane + 64]);
        bf16* dst;
        if (rr < 16) dst = Qr + ((size_t)(b * Hh + rr) * Tt + t) * 128;
        else         dst = Kr + ((size_t)(b * Gg + (rr - 16)) * Tt + t) * 128;
        float ssum = x1 * x1 + x2 * x2;
        #pragma unroll
        for (int o = 32; o > 0; o >>= 1) ssum += __shfl_xor(ssum, o);
        const float inv = rsqrtf(ssum * (1.0f / 128.0f) + 1e-6f);
        const float post = (rr < 16) ? 0.08838834764831845f : 1.0f;  // fold 1/sqrt(D) into Q
        const float sc1 = ((rr < 16) ? qs1 : ks1) * inv;
        const float sc2 = ((rr < 16) ? qs2 : ks2) * inv;
        const float y1 = x1 * sc1;
        const float y2 = x2 * sc2;
        dst[lane]      = __float2bfloat16((y1 * c1 - y2 * s1) * post);
        dst[lane + 64] = __float2bfloat16((y2 * c2 + y1 * s2) * post);
    }
}

// ---------------- causal flash attention (round-4 proven, 67.5 us) ----------------
__global__ __launch_bounds__(256)
void k_attn(const bf16* __restrict__ Qr, const bf16* __restrict__ Kr,
            const bf16* __restrict__ Vt, bf16* __restrict__ AO) {
    __shared__ __align__(16) bf16 Ksm[2][64 * 128];
    __shared__ __align__(16) bf16 Vsm[2][128 * 64];
    __shared__ __align__(16) bf16 Psm[4][16 * 64];
    const int id = blockIdx.x;
    const int bg = id & 7;
    const int wid = id >> 3;
    const int pair = wid & 15;
    const int hg = wid >> 4;
    const int b = bg >> 2, g = bg & 3;
    const int h = g * 4 + hg;
    const int lane = threadIdx.x & 63;
    const int wave = threadIdx.x >> 6;

    const bf16* Kbase = Kr + (size_t)(b * Gg + g) * Tt * Dd;
    const bf16* Vbase = Vt + (size_t)(b * Gg + g) * Dd * Tt;

    for (int pass = 0; pass < 2; ++pass) {
        const int qt = pass ? (31 - pair) : pair;
        const bf16* Qbase = Qr + ((size_t)(b * Hh + h) * Tt + qt * 64) * Dd;

        short8 qf[4];
        #pragma unroll
        for (int kk = 0; kk < 4; ++kk)
            qf[kk] = *(const short8*)(Qbase + (size_t)(wave * 16 + (lane & 15)) * 128 + kk * 32 + (lane >> 4) * 8);

        float l_run[4] = {0.f, 0.f, 0.f, 0.f};
        f32x4 oacc[8];
        #pragma unroll
        for (int j = 0; j < 8; ++j) oacc[j] = (f32x4){0.f, 0.f, 0.f, 0.f};

        {
            #pragma unroll
            for (int j = 0; j < 4; ++j) {
                const int c = j * 4 + wave;
                const int rtk = c * 4 + (lane >> 4);
                const int chk = (lane & 15) ^ (rtk & 7);
                gload_lds16(Kbase + (size_t)rtk * 128 + chk * 8, Ksm[0] + c * 512);
                const int rtv = c * 8 + (lane >> 3);
                const int chv = (lane & 7) ^ ((lane >> 3) & 7);
                gload_lds16(Vbase + (size_t)rtv * Tt + chv * 8, Vsm[0] + c * 512);
            }
        }

        int cur = 0;
        const int nkv = qt + 1;
        for (int tk = 0; tk < nkv; ++tk) {
            __syncthreads();

            if (tk + 1 < nkv) {
                const int k0n = (tk + 1) * 64;
                #pragma unroll
                for (int j = 0; j < 4; ++j) {
                    const int c = j * 4 + wave;
                    const int rtk = c * 4 + (lane >> 4);
                    const int chk = (lane & 15) ^ (rtk & 7);
                    gload_lds16(Kbase + (size_t)(k0n + rtk) * 128 + chk * 8, Ksm[cur ^ 1] + c * 512);
                    const int rtv = c * 8 + (lane >> 3);
                    const int chv = (lane & 7) ^ ((lane >> 3) & 7);
                    gload_lds16(Vbase + (size_t)rtv * Tt + k0n + chv * 8, Vsm[cur ^ 1] + c * 512);
                }
            }

            const bf16* Ks = Ksm[cur];
            const bf16* Vs = Vsm[cur];

            f32x4 s[4];
            #pragma unroll
            for (int nt = 0; nt < 4; ++nt) s[nt] = (f32x4){0.f, 0.f, 0.f, 0.f};
            __builtin_amdgcn_s_setprio(1);
            #pragma unroll
            for (int nt = 0; nt < 4; ++nt) {
                #pragma unroll
                for (int kk = 0; kk < 4; ++kk) {
                    const int rk = nt * 16 + (lane & 15);
                    short8 kf = *(const short8*)((const char*)Ks + rk * 256 +
                                ((kk * 64 + (lane >> 4) * 16) ^ ((rk & 7) << 4)));
                    s[nt] = __builtin_amdgcn_mfma_f32_16x16x32_bf16(qf[kk], kf, s[nt], 0, 0, 0);
                }
            }
            __builtin_amdgcn_s_setprio(0);

            if (tk == nkv - 1) {
                const int qrow = qt * 64 + wave * 16 + (lane >> 4) * 4;
                const int k0 = tk * 64;
                #pragma unroll
                for (int nt = 0; nt < 4; ++nt) {
                    const int kcol = k0 + nt * 16 + (lane & 15);
                    #pragma unroll
                    for (int r = 0; r < 4; ++r)
                        if (kcol > qrow + r) s[nt][r] = -1e30f;
                }
            }

            #pragma unroll
            for (int nt = 0; nt < 4; ++nt)
                #pragma unroll
                for (int r = 0; r < 4; ++r) {
                    const float p = __expf(s[nt][r]);
                    l_run[r] += p;
                    s[nt][r] = p;
                }

            #pragma unroll
            for (int nt = 0; nt < 4; ++nt)
                #pragma unroll
                for (int r = 0; r < 4; ++r) {
                    const int prow = (lane >> 4) * 4 + r;
                    const int pcol = nt * 16 + (lane & 15);
                    *(bf16*)((char*)Psm[wave] + ((prow * 128 + pcol * 2) ^ ((prow & 7) << 4))) =
                        __float2bfloat16(s[nt][r]);
                }
            #pragma unroll
            for (int kk = 0; kk < 2; ++kk) {
                const int pr = lane & 15;
                short8 pf = *(const short8*)((const char*)Psm[wave] + pr * 128 +
                            ((kk * 64 + (lane >> 4) * 16) ^ ((pr & 7) << 4)));
                __builtin_amdgcn_s_setprio(1);
                #pragma unroll
                for (int j = 0; j < 8; ++j) {
                    const int rb = j * 16 + (lane & 15);
                    short8 vf = *(const short8*)((const char*)Vs + rb * 128 +
                                ((kk * 64 + (lane >> 4) * 16) ^ ((rb & 7) << 4)));
                    oacc[j] = __builtin_amdgcn_mfma_f32_16x16x32_bf16(pf, vf, oacc[j], 0, 0, 0);
                }
                __builtin_amdgcn_s_setprio(0);
            }
            cur ^= 1;
        }
        __syncthreads();

        #pragma unroll
        for (int o = 1; o < 16; o <<= 1)
            #pragma unroll
            for (int r = 0; r < 4; ++r) l_run[r] += __shfl_xor(l_run[r], o);

        #pragma unroll
        for (int r = 0; r < 4; ++r) {
            const float inv = 1.0f / l_run[r];
            const int qrow = qt * 64 + wave * 16 + (lane >> 4) * 4 + r;
            bf16* dst = AO + (size_t)(b * Tt + qrow) * 2048 + h * 128 + (lane & 15);
            #pragma unroll
            for (int j = 0; j < 8; ++j)
                dst[j * 16] = __float2bfloat16(oacc[j][r] * inv);
        }
    }
}

extern "C" void kernel_launch(void* const* d_in, const int* in_sizes, int n_in,
                              void* d_out, int out_size, void* d_ws, size_t ws_size,
                              hipStream_t stream) {
    const float* x    = (const float*)d_in[0];
    const float* cosT = (const float*)d_in[2];
    const float* sinT = (const float*)d_in[3];
    const float* Wq   = (const float*)d_in[4];
    const float* Wk   = (const float*)d_in[5];
    const float* Wv   = (const float*)d_in[6];
    const float* Wo   = (const float*)d_in[7];
    const float* qs   = (const float*)d_in[8];
    const float* ks   = (const float*)d_in[9];

    char* ws = (char*)d_ws;
    bf16* xb   = (bf16*)(ws);                    // 16.78 MB
    bf16* Wcat = (bf16*)(ws + 16777216);         // [3072][2048] 12.58 MB
    bf16* Wot  = (bf16*)(ws + 29360128);         // [2048][2048] 8.39 MB
    bf16* QKV  = (bf16*)(ws + 37748736);         // [4096][3072] 25.17 MB
    bf16* Qr   = (bf16*)(ws + 62914560);         // [B][H][T][D] 16.78 MB
    bf16* Kr   = (bf16*)(ws + 79691776);         // [B][G][T][D] 4.19 MB
    bf16* Vtp  = (bf16*)(ws + 83886080);         // [B][G][D][T] 4.19 MB
    bf16* AO   = (bf16*)(ws + 88080384);         // [B*T][H*D]  16.78 MB

    k_cast_bf16<<<8192, 256, 0, stream>>>(x, xb, 2097152);
    dim3 tb(32, 8);
    k_cast_transpose<<<dim3(64, 64), tb, 0, stream>>>(Wq, Wcat, 2048, 2048, 2048);
    k_cast_transpose<<<dim3(16, 64), tb, 0, stream>>>(Wk, Wcat + (size_t)2048 * 2048, 2048, 512, 2048);
    k_cast_transpose<<<dim3(16, 64), tb, 0, stream>>>(Wv, Wcat + (size_t)2560 * 2048, 2048, 512, 2048);
    k_cast_transpose<<<dim3(64, 64), tb, 0, stream>>>(Wo, Wot, 2048, 2048, 2048);

    k_gemm256<0><<<192, 512, 0, stream>>>(xb, Wcat, QKV, 4096, 3072, 2048, 12);
    k_qkv_post<<<4096, 256, 0, stream>>>(QKV, cosT, sinT, qs, ks, Qr, Kr);
    k_vt<<<dim3(2, 32, 8), dim3(64, 8), 0, stream>>>(QKV, Vtp);
    k_attn<<<512, 256, 0, stream>>>(Qr, Kr, Vtp, AO);
    k_gemm_bt<1><<<dim3(16, 32), 256, 0, stream>>>(AO, Wot, d_out, 4096, 2048, 2048);
}